// Round 4
// baseline (828.537 us; speedup 1.0000x reference)
//
#include <hip/hip_runtime.h>
#include <hip/hip_bf16.h>
#include <math.h>

// Problem constants: N=8192, IN_DIM=1024, H1=512, H2=256, Z=192
#define NN 8192
#define CAP 256   // max nnz/row stored; actual ~34

typedef __attribute__((ext_vector_type(8))) short short8;
typedef __attribute__((ext_vector_type(16))) float f32x16;

// ---------------------------------------------------------------------------
// helpers: fp32 <-> bf16 hi/lo split
// ---------------------------------------------------------------------------
static __device__ __forceinline__ unsigned short f2bf(float f) {
    __hip_bfloat16 h = __float2bfloat16(f);
    return *reinterpret_cast<unsigned short*>(&h);
}
static __device__ __forceinline__ float bf2f(unsigned short u) {
    __hip_bfloat16 h = *reinterpret_cast<__hip_bfloat16*>(&u);
    return __bfloat162float(h);
}

// ---------------------------------------------------------------------------
// Kernel 1: scan dense adj (256 MB) once, build padded-CSR (cols u16, vals f32)
// ---------------------------------------------------------------------------
__global__ __launch_bounds__(256) void build_csr(
    const float* __restrict__ adj, unsigned short* __restrict__ cols,
    float* __restrict__ vals, int* __restrict__ cnt)
{
    const int row = blockIdx.x;
    const int tid = threadIdx.x;
    __shared__ int c;
    if (tid == 0) c = 0;
    __syncthreads();
    const float4* arow = (const float4*)(adj + (size_t)row * NN);
    for (int i = tid; i < NN / 4; i += 256) {
        const float4 v = arow[i];
        const int base = i * 4;
        if (v.x != 0.f) { int p = atomicAdd(&c, 1); if (p < CAP) { cols[(size_t)row*CAP+p] = (unsigned short)(base+0); vals[(size_t)row*CAP+p] = v.x; } }
        if (v.y != 0.f) { int p = atomicAdd(&c, 1); if (p < CAP) { cols[(size_t)row*CAP+p] = (unsigned short)(base+1); vals[(size_t)row*CAP+p] = v.y; } }
        if (v.z != 0.f) { int p = atomicAdd(&c, 1); if (p < CAP) { cols[(size_t)row*CAP+p] = (unsigned short)(base+2); vals[(size_t)row*CAP+p] = v.z; } }
        if (v.w != 0.f) { int p = atomicAdd(&c, 1); if (p < CAP) { cols[(size_t)row*CAP+p] = (unsigned short)(base+3); vals[(size_t)row*CAP+p] = v.w; } }
    }
    __syncthreads();
    if (tid == 0) cnt[row] = min(c, CAP);
}

// ---------------------------------------------------------------------------
// Kernel 2: SpMM  out[row,:] = sum_k val_k * H[col_k,:]
// fused epilogue: optional relu, sigmoid copy, fp32 out, bf16 hi/lo pack
// ---------------------------------------------------------------------------
template <int COLS, int RELU, int WSIG, int WOUT, int WHILO>
__global__ void spmm_kernel(
    const unsigned short* __restrict__ cols, const float* __restrict__ vals,
    const int* __restrict__ cnt, const float* __restrict__ H,
    float* __restrict__ out, float* __restrict__ sig_out,
    unsigned short* __restrict__ hi, unsigned short* __restrict__ lo)
{
    const int row = blockIdx.x;
    const int tid = threadIdx.x;
    __shared__ unsigned short lc[CAP];
    __shared__ float lv[CAP];
    const int n = cnt[row];
    for (int i = tid; i < n; i += COLS) {
        lc[i] = cols[(size_t)row * CAP + i];
        lv[i] = vals[(size_t)row * CAP + i];
    }
    __syncthreads();
    float acc = 0.f;
    int k = 0;
    for (; k + 4 <= n; k += 4) {
        const float a0 = lv[k+0] * H[(size_t)lc[k+0] * COLS + tid];
        const float a1 = lv[k+1] * H[(size_t)lc[k+1] * COLS + tid];
        const float a2 = lv[k+2] * H[(size_t)lc[k+2] * COLS + tid];
        const float a3 = lv[k+3] * H[(size_t)lc[k+3] * COLS + tid];
        acc += (a0 + a1) + (a2 + a3);
    }
    for (; k < n; ++k) acc += lv[k] * H[(size_t)lc[k] * COLS + tid];
    if (RELU) acc = fmaxf(acc, 0.f);
    const size_t idx = (size_t)row * COLS + tid;
    if (WOUT) out[idx] = acc;
    if (WSIG) sig_out[idx] = 1.f / (1.f + expf(-acc));
    if (WHILO) {
        const unsigned short h = f2bf(acc);
        hi[idx] = h;
        lo[idx] = f2bf(acc - bf2f(h));
    }
}

// ---------------------------------------------------------------------------
// Kernel 3: pack fp32 -> bf16 hi/lo pair (inputs only)
// ---------------------------------------------------------------------------
__global__ __launch_bounds__(256) void pack_hilo(
    const float* __restrict__ in, unsigned short* __restrict__ hi,
    unsigned short* __restrict__ lo, int n4)   // n4 = n/4
{
    for (int idx = blockIdx.x * 256 + threadIdx.x; idx < n4; idx += gridDim.x * 256) {
        const float4 v = ((const float4*)in)[idx];
        float f[4] = {v.x, v.y, v.z, v.w};
        ushort4 h, l;
        unsigned short* hp = (unsigned short*)&h;
        unsigned short* lp = (unsigned short*)&l;
        #pragma unroll
        for (int j = 0; j < 4; ++j) {
            const unsigned short hb = f2bf(f[j]);
            hp[j] = hb;
            lp[j] = f2bf(f[j] - bf2f(hb));
        }
        ((ushort4*)hi)[idx] = h;
        ((ushort4*)lo)[idx] = l;
    }
}

// ---------------------------------------------------------------------------
// Kernel 4: bf16x3-split MFMA GEMM   C[M,Nb] = A[M,K] * B[Nb,K]^T (fp32 acc)
// hi*hi + lo*hi + hi*lo over 3 K-passes. Tile BM x BN, 4 waves in WM x WN grid,
// mfma_f32_32x32x16_bf16, BK=64, global_load_lds w16, XOR swizzle on source.
// EPI: 0 = fp32 C;  1 = +bias, leaky_relu(0.1), write bf16 hi/lo pair
// ---------------------------------------------------------------------------
template <int BM, int BN, int WM, int WN, int EPI>
__global__ __launch_bounds__(256) void gemm3(
    const unsigned short* __restrict__ Ahi, const unsigned short* __restrict__ Alo,
    const unsigned short* __restrict__ Bhi, const unsigned short* __restrict__ Blo,
    float* __restrict__ C, unsigned short* __restrict__ Ohi,
    unsigned short* __restrict__ Olo, const float* __restrict__ bias,
    int K, int Nb, int ldC)
{
    constexpr int FM = BM / (WM * 32);   // 32x32 fragment repeats per wave (M)
    constexpr int FN = BN / (WN * 32);   // (N)
    __shared__ __align__(16) unsigned short As[BM * 64];
    __shared__ __align__(16) unsigned short Bs[BN * 64];
    const int bm = blockIdx.x * BM;
    const int bn = blockIdx.y * BN;
    const int tid = threadIdx.x;
    const int lane = tid & 63;
    const int wave = tid >> 6;
    const int wr = wave / WN, wc = wave % WN;

    f32x16 acc[FM][FN] = {};

    for (int seg = 0; seg < 3; ++seg) {
        const unsigned short* Aseg = (seg == 1) ? Alo : Ahi;
        const unsigned short* Bseg = (seg == 2) ? Blo : Bhi;
        for (int kt = 0; kt < K; kt += 64) {
            // ---- stage A tile [BM rows][64 bf16], swizzled source (rule #21)
            #pragma unroll
            for (int call = 0; call < BM / 32; ++call) {
                const int c = call * 256 + tid;          // 16B chunk id
                const int row = c >> 3;
                const int slot = (c & 7) ^ (row & 7);    // inverse-swizzle source
                const unsigned short* g = Aseg + (size_t)(bm + row) * K + kt + slot * 8;
                __builtin_amdgcn_global_load_lds(
                    (const __attribute__((address_space(1))) unsigned int*)g,
                    (__attribute__((address_space(3))) unsigned int*)&As[c * 8], 16, 0, 0);
            }
            // ---- stage B tile [BN rows][64 bf16] (row clamp for partial tiles)
            #pragma unroll
            for (int call = 0; call < BN / 32; ++call) {
                const int c = call * 256 + tid;
                const int row = c >> 3;
                const int slot = (c & 7) ^ (row & 7);
                int rg = bn + row; rg = rg < Nb ? rg : Nb - 1;
                const unsigned short* g = Bseg + (size_t)rg * K + kt + slot * 8;
                __builtin_amdgcn_global_load_lds(
                    (const __attribute__((address_space(1))) unsigned int*)g,
                    (__attribute__((address_space(3))) unsigned int*)&Bs[c * 8], 16, 0, 0);
            }
            __syncthreads();
            // ---- compute: 4 K-substeps of 16
            #pragma unroll
            for (int ks = 0; ks < 4; ++ks) {
                const int q = ks * 2 + (lane >> 5);      // 16B chunk within row
                short8 a[FM], b[FN];
                #pragma unroll
                for (int m = 0; m < FM; ++m) {
                    const int row = wr * (BM / WM) + m * 32 + (lane & 31);
                    const int s = q ^ (row & 7);         // swizzled read
                    a[m] = *(const short8*)&As[row * 64 + s * 8];
                }
                #pragma unroll
                for (int n = 0; n < FN; ++n) {
                    const int row = wc * (BN / WN) + n * 32 + (lane & 31);
                    const int s = q ^ (row & 7);
                    b[n] = *(const short8*)&Bs[row * 64 + s * 8];
                }
                #pragma unroll
                for (int m = 0; m < FM; ++m)
                    #pragma unroll
                    for (int n = 0; n < FN; ++n)
                        acc[m][n] = __builtin_amdgcn_mfma_f32_32x32x16_bf16(
                            a[m], b[n], acc[m][n], 0, 0, 0);
            }
            __syncthreads();
        }
    }
    // ---- epilogue: C/D layout col=lane&31, row=(reg&3)+8*(reg>>2)+4*(lane>>5)
    const int hl = lane >> 5;
    #pragma unroll
    for (int m = 0; m < FM; ++m) {
        #pragma unroll
        for (int n = 0; n < FN; ++n) {
            const int col = bn + wc * (BN / WN) + n * 32 + (lane & 31);
            if (col < Nb) {
                #pragma unroll
                for (int r = 0; r < 16; ++r) {
                    const int rl = (r & 3) + 8 * (r >> 2) + 4 * hl;
                    const size_t row = bm + wr * (BM / WM) + m * 32 + rl;
                    float v = acc[m][n][r];
                    if (EPI == 1) {
                        v += bias[col];
                        v = v > 0.f ? v : 0.1f * v;
                        const unsigned short h = f2bf(v);
                        Ohi[row * (size_t)ldC + col] = h;
                        Olo[row * (size_t)ldC + col] = f2bf(v - bf2f(h));
                    } else {
                        C[row * (size_t)ldC + col] = v;
                    }
                }
            }
        }
    }
}

// ---------------------------------------------------------------------------
// Fallback fp32 GEMM (proven path, used only if ws_size too small)
// ---------------------------------------------------------------------------
template <int ACT>
__global__ __launch_bounds__(256) void gemm_abt(
    const float* __restrict__ A, const float* __restrict__ B,
    float* __restrict__ C, const float* __restrict__ bias,
    int K, int ldC)
{
    __shared__ float As[16][132];
    __shared__ float Bs[16][68];
    const int bm = blockIdx.x * 128;
    const int bn = blockIdx.y * 64;
    const int tid = threadIdx.x;
    const int ty = tid >> 4;
    const int tx = tid & 15;
    float acc[8][4] = {};
    const float* Ab = A + (size_t)bm * K;
    const float* Bb = B + (size_t)bn * K;
    for (int kt = 0; kt < K; kt += 16) {
        #pragma unroll
        for (int j = 0; j < 2; ++j) {
            const int i = tid * 2 + j;
            const int row = i >> 2, kq = i & 3;
            const float4 v = *(const float4*)(Ab + (size_t)row * K + kt + kq * 4);
            As[kq*4+0][row] = v.x; As[kq*4+1][row] = v.y;
            As[kq*4+2][row] = v.z; As[kq*4+3][row] = v.w;
        }
        {
            const int row = tid >> 2, kq = tid & 3;
            const float4 v = *(const float4*)(Bb + (size_t)row * K + kt + kq * 4);
            Bs[kq*4+0][row] = v.x; Bs[kq*4+1][row] = v.y;
            Bs[kq*4+2][row] = v.z; Bs[kq*4+3][row] = v.w;
        }
        __syncthreads();
        #pragma unroll
        for (int kk = 0; kk < 16; ++kk) {
            float a[8], b[4];
            #pragma unroll
            for (int i2 = 0; i2 < 8; ++i2) a[i2] = As[kk][ty*8 + i2];
            #pragma unroll
            for (int j2 = 0; j2 < 4; ++j2) b[j2] = Bs[kk][tx*4 + j2];
            #pragma unroll
            for (int i2 = 0; i2 < 8; ++i2)
                #pragma unroll
                for (int j2 = 0; j2 < 4; ++j2)
                    acc[i2][j2] = fmaf(a[i2], b[j2], acc[i2][j2]);
        }
        __syncthreads();
    }
    #pragma unroll
    for (int i2 = 0; i2 < 8; ++i2) {
        const size_t r = bm + ty*8 + i2;
        #pragma unroll
        for (int j2 = 0; j2 < 4; ++j2) {
            const int cidx = bn + tx*4 + j2;
            float v = acc[i2][j2];
            if (ACT == 1) { v += bias[cidx]; v = v > 0.f ? v : 0.1f * v; }
            C[r * (size_t)ldC + cidx] = v;
        }
    }
}

// ---------------------------------------------------------------------------
extern "C" void kernel_launch(void* const* d_in, const int* in_sizes, int n_in,
                              void* d_out, int out_size, void* d_ws, size_t ws_size,
                              hipStream_t stream)
{
    const float* adj = (const float*)d_in[0];
    const float* x   = (const float*)d_in[1];
    const float* W1  = (const float*)d_in[2];  // [512,1024]
    const float* W2  = (const float*)d_in[3];  // [256,512]
    const float* Wm1 = (const float*)d_in[4];  // [64,256]
    const float* Wm2 = (const float*)d_in[5];
    const float* Wm3 = (const float*)d_in[6];
    const float* Wt  = (const float*)d_in[7];  // [192,192]
    const float* bt  = (const float*)d_in[8];  // [192]
    float* out = (float*)d_out;

    // output layout (flat, return order): pred, sigmoid(x1), sigmoid(x2), z
    float* pred = out;                       // 8192*8192
    float* sig1 = out + 67108864;            // 8192*512
    float* sig2 = sig1 + 4194304;            // 8192*256
    float* z    = sig2 + 2097152;            // 8192*192

    // ---- workspace layout (bf16x3 path): ~78 MB
    char* w = (char*)d_ws;
    float* F  = (float*)w;                     w += (size_t)8192*512*4;      // 16 MB fp32 scratch
    unsigned short* Xhi = (unsigned short*)w;  w += (size_t)8192*1024*2;     // 16 MB
    unsigned short* Xlo = (unsigned short*)w;  w += (size_t)8192*1024*2;     // 16 MB
    unsigned short* Whi = (unsigned short*)w;  w += (size_t)512*1024*2;      // 1 MB
    unsigned short* Wlo = (unsigned short*)w;  w += (size_t)512*1024*2;      // 1 MB
    unsigned short* Zhi = (unsigned short*)w;  w += (size_t)8192*192*2;      // 3 MB
    unsigned short* Zlo = (unsigned short*)w;  w += (size_t)8192*192*2;
    unsigned short* Thi = (unsigned short*)w;  w += (size_t)8192*192*2;
    unsigned short* Tlo = (unsigned short*)w;  w += (size_t)8192*192*2;
    float* vals = (float*)w;                   w += (size_t)NN*CAP*4;        // 8 MB
    unsigned short* cols = (unsigned short*)w; w += (size_t)NN*CAP*2;        // 4 MB
    int* cnt = (int*)w;                        w += (size_t)NN*4;
    const size_t need = (size_t)(w - (char*)d_ws);

    if (ws_size < need) {
        // -------- fallback: proven fp32 path (needs ~46 MB) --------
        float* bufA = (float*)d_ws;
        float* bufB = bufA + 4194304;
        float* fvals = bufB + 4194304;
        unsigned short* fcols = (unsigned short*)(fvals + (size_t)NN * CAP);
        int* fcnt = (int*)(fcols + (size_t)NN * CAP);
        build_csr<<<NN, 256, 0, stream>>>(adj, fcols, fvals, fcnt);
        gemm_abt<0><<<dim3(64, 8), 256, 0, stream>>>(x, W1, bufA, nullptr, 1024, 512);
        spmm_kernel<512, 1, 1, 1, 0><<<NN, 512, 0, stream>>>(fcols, fvals, fcnt, bufA, bufB, sig1, nullptr, nullptr);
        gemm_abt<0><<<dim3(64, 4), 256, 0, stream>>>(bufB, W2, bufA, nullptr, 512, 256);
        spmm_kernel<256, 1, 1, 1, 0><<<NN, 256, 0, stream>>>(fcols, fvals, fcnt, bufA, bufB, sig2, nullptr, nullptr);
        gemm_abt<0><<<dim3(64, 1), 256, 0, stream>>>(bufB, Wm1, bufA +   0, nullptr, 256, 192);
        gemm_abt<0><<<dim3(64, 1), 256, 0, stream>>>(bufB, Wm2, bufA +  64, nullptr, 256, 192);
        gemm_abt<0><<<dim3(64, 1), 256, 0, stream>>>(bufB, Wm3, bufA + 128, nullptr, 256, 192);
        spmm_kernel<192, 0, 0, 1, 0><<<NN, 192, 0, stream>>>(fcols, fvals, fcnt, bufA, z, nullptr, nullptr, nullptr);
        gemm_abt<1><<<dim3(64, 3), 256, 0, stream>>>(z, Wt, bufB, bt, 192, 192);
        gemm_abt<0><<<dim3(64, 128), 256, 0, stream>>>(z, bufB, pred, nullptr, 192, 8192);
        return;
    }

    // -------- bf16x3 MFMA path --------
    build_csr<<<NN, 256, 0, stream>>>(adj, cols, vals, cnt);

    // layer 1: x1 = relu(adj @ (x @ W1^T)); sig1 = sigmoid(x1); x1 -> Xhi/Xlo
    pack_hilo<<<2048, 256, 0, stream>>>(x,  Xhi, Xlo, 8192*1024/4);
    pack_hilo<<<512,  256, 0, stream>>>(W1, Whi, Wlo, 512*1024/4);
    gemm3<64, 128, 2, 2, 0><<<dim3(128, 4), 256, 0, stream>>>(
        Xhi, Xlo, Whi, Wlo, F, nullptr, nullptr, nullptr, 1024, 512, 512);
    spmm_kernel<512, 1, 1, 0, 1><<<NN, 512, 0, stream>>>(
        cols, vals, cnt, F, nullptr, sig1, Xhi, Xlo);

    // layer 2: x2 = relu(adj @ (x1 @ W2^T)); sig2 = sigmoid(x2); x2 -> Xhi/Xlo
    pack_hilo<<<128, 256, 0, stream>>>(W2, Whi, Wlo, 256*512/4);
    gemm3<64, 128, 2, 2, 0><<<dim3(128, 2), 256, 0, stream>>>(
        Xhi, Xlo, Whi, Wlo, F, nullptr, nullptr, nullptr, 512, 256, 256);
    spmm_kernel<256, 1, 1, 0, 1><<<NN, 256, 0, stream>>>(
        cols, vals, cnt, F, nullptr, sig2, Xhi, Xlo);

    // heads: z = adj @ (x2 @ [Wm1;Wm2;Wm3]^T); z fp32 out + Zhi/Zlo
    pack_hilo<<<16, 256, 0, stream>>>(Wm1, Whi,           Wlo,           64*256/4);
    pack_hilo<<<16, 256, 0, stream>>>(Wm2, Whi +  64*256, Wlo +  64*256, 64*256/4);
    pack_hilo<<<16, 256, 0, stream>>>(Wm3, Whi + 128*256, Wlo + 128*256, 64*256/4);
    gemm3<64, 64, 2, 2, 0><<<dim3(128, 3), 256, 0, stream>>>(
        Xhi, Xlo, Whi, Wlo, F, nullptr, nullptr, nullptr, 256, 192, 192);
    spmm_kernel<192, 0, 0, 1, 1><<<NN, 192, 0, stream>>>(
        cols, vals, cnt, F, z, nullptr, Zhi, Zlo);

    // trans_z = leaky_relu(z @ Wt^T + bt) -> Thi/Tlo directly (fused epilogue)
    pack_hilo<<<36, 256, 0, stream>>>(Wt, Whi, Wlo, 192*192/4);
    gemm3<64, 64, 2, 2, 1><<<dim3(128, 3), 256, 0, stream>>>(
        Zhi, Zlo, Whi, Wlo, nullptr, Thi, Tlo, bt, 192, 192, 192);

    // pred = z @ trans_z^T  [8192 x 8192], 256x128 tile for arithmetic intensity
    gemm3<256, 128, 2, 2, 0><<<dim3(32, 64), 256, 0, stream>>>(
        Zhi, Zlo, Thi, Tlo, pred, nullptr, nullptr, nullptr, 192, 8192, 8192);
}

// Round 7
// 690.024 us; speedup vs baseline: 1.2007x; 1.2007x over previous
//
#include <hip/hip_runtime.h>
#include <hip/hip_bf16.h>
#include <hip/hip_fp16.h>
#include <math.h>

// Problem constants: N=8192, IN_DIM=1024, H1=512, H2=256, Z=192
#define NN 8192
#define CAP 256   // max nnz/row stored; actual ~34

typedef __attribute__((ext_vector_type(8))) _Float16 half8;
typedef __attribute__((ext_vector_type(16))) float f32x16;

// ---------------------------------------------------------------------------
// helpers
// ---------------------------------------------------------------------------
static __device__ __forceinline__ unsigned short f2h(float f) {
    __half h = __float2half(f);
    return *reinterpret_cast<unsigned short*>(&h);
}

// ---------------------------------------------------------------------------
// Kernel 1: scan dense adj (256 MB) once, build padded-CSR (cols u16, vals f32)
// ---------------------------------------------------------------------------
__global__ __launch_bounds__(256) void build_csr(
    const float* __restrict__ adj, unsigned short* __restrict__ cols,
    float* __restrict__ vals, int* __restrict__ cnt)
{
    const int row = blockIdx.x;
    const int tid = threadIdx.x;
    __shared__ int c;
    if (tid == 0) c = 0;
    __syncthreads();
    const float4* arow = (const float4*)(adj + (size_t)row * NN);
    for (int i = tid; i < NN / 4; i += 256) {
        const float4 v = arow[i];
        const int base = i * 4;
        if (v.x != 0.f) { int p = atomicAdd(&c, 1); if (p < CAP) { cols[(size_t)row*CAP+p] = (unsigned short)(base+0); vals[(size_t)row*CAP+p] = v.x; } }
        if (v.y != 0.f) { int p = atomicAdd(&c, 1); if (p < CAP) { cols[(size_t)row*CAP+p] = (unsigned short)(base+1); vals[(size_t)row*CAP+p] = v.y; } }
        if (v.z != 0.f) { int p = atomicAdd(&c, 1); if (p < CAP) { cols[(size_t)row*CAP+p] = (unsigned short)(base+2); vals[(size_t)row*CAP+p] = v.z; } }
        if (v.w != 0.f) { int p = atomicAdd(&c, 1); if (p < CAP) { cols[(size_t)row*CAP+p] = (unsigned short)(base+3); vals[(size_t)row*CAP+p] = v.w; } }
    }
    __syncthreads();
    if (tid == 0) cnt[row] = min(c, CAP);
}

// ---------------------------------------------------------------------------
// Kernel 2: SpMM  out[row,:] = sum_k val_k * H[col_k,:]
// fused epilogue: optional relu, sigmoid copy, fp32 out, fp16 pack
// ---------------------------------------------------------------------------
template <int COLS, int RELU, int WSIG, int WOUT, int WH16>
__global__ void spmm_kernel(
    const unsigned short* __restrict__ cols, const float* __restrict__ vals,
    const int* __restrict__ cnt, const float* __restrict__ H,
    float* __restrict__ out, float* __restrict__ sig_out,
    unsigned short* __restrict__ h16)
{
    const int row = blockIdx.x;
    const int tid = threadIdx.x;
    __shared__ unsigned short lc[CAP];
    __shared__ float lv[CAP];
    const int n = cnt[row];
    for (int i = tid; i < n; i += COLS) {
        lc[i] = cols[(size_t)row * CAP + i];
        lv[i] = vals[(size_t)row * CAP + i];
    }
    __syncthreads();
    float acc = 0.f;
    int k = 0;
    for (; k + 4 <= n; k += 4) {
        const float a0 = lv[k+0] * H[(size_t)lc[k+0] * COLS + tid];
        const float a1 = lv[k+1] * H[(size_t)lc[k+1] * COLS + tid];
        const float a2 = lv[k+2] * H[(size_t)lc[k+2] * COLS + tid];
        const float a3 = lv[k+3] * H[(size_t)lc[k+3] * COLS + tid];
        acc += (a0 + a1) + (a2 + a3);
    }
    for (; k < n; ++k) acc += lv[k] * H[(size_t)lc[k] * COLS + tid];
    if (RELU) acc = fmaxf(acc, 0.f);
    const size_t idx = (size_t)row * COLS + tid;
    if (WOUT) out[idx] = acc;
    if (WSIG) sig_out[idx] = 1.f / (1.f + expf(-acc));
    if (WH16) h16[idx] = f2h(acc);
}

// ---------------------------------------------------------------------------
// Kernel 3: pack fp32 -> fp16 (inputs only)
// ---------------------------------------------------------------------------
__global__ __launch_bounds__(256) void pack_f16(
    const float* __restrict__ in, unsigned short* __restrict__ h, int n4)  // n4 = n/4
{
    for (int idx = blockIdx.x * 256 + threadIdx.x; idx < n4; idx += gridDim.x * 256) {
        const float4 v = ((const float4*)in)[idx];
        ushort4 o;
        o.x = f2h(v.x); o.y = f2h(v.y); o.z = f2h(v.z); o.w = f2h(v.w);
        ((ushort4*)h)[idx] = o;
    }
}

// ---------------------------------------------------------------------------
// Kernel 4: fp16 single-pass MFMA GEMM   C[M,Nb] = A[M,K] * B[Nb,K]^T (fp32 acc)
// Tile BM x BN, 4 waves in WM x WN grid, mfma_f32_32x32x16_f16, BK=64,
// global_load_lds w16 staging, XOR swizzle on source addr (rule #21).
// EPI: 0 = fp32 C;  1 = +bias, leaky_relu(0.1), write fp16 to Oh
// ---------------------------------------------------------------------------
template <int BM, int BN, int WM, int WN, int EPI>
__global__ __launch_bounds__(256) void gemm_f16(
    const unsigned short* __restrict__ A, const unsigned short* __restrict__ B,
    float* __restrict__ C, unsigned short* __restrict__ Oh,
    const float* __restrict__ bias, int K, int Nb, int ldC)
{
    constexpr int FM = BM / (WM * 32);   // 32x32 fragment repeats per wave (M)
    constexpr int FN = BN / (WN * 32);   // (N)
    __shared__ __align__(16) unsigned short As[BM * 64];
    __shared__ __align__(16) unsigned short Bs[BN * 64];
    const int bm = blockIdx.x * BM;
    const int bn = blockIdx.y * BN;
    const int tid = threadIdx.x;
    const int lane = tid & 63;
    const int wave = tid >> 6;
    const int wr = wave / WN, wc = wave % WN;

    f32x16 acc[FM][FN] = {};

    for (int kt = 0; kt < K; kt += 64) {
        // ---- stage A tile [BM rows][64 fp16], swizzled source (rule #21)
        #pragma unroll
        for (int call = 0; call < BM / 32; ++call) {
            const int c = call * 256 + tid;          // 16B chunk id
            const int row = c >> 3;
            const int slot = (c & 7) ^ (row & 7);    // inverse-swizzle source
            const unsigned short* g = A + (size_t)(bm + row) * K + kt + slot * 8;
            __builtin_amdgcn_global_load_lds(
                (const __attribute__((address_space(1))) unsigned int*)g,
                (__attribute__((address_space(3))) unsigned int*)&As[c * 8], 16, 0, 0);
        }
        // ---- stage B tile [BN rows][64 fp16] (row clamp for partial tiles)
        #pragma unroll
        for (int call = 0; call < BN / 32; ++call) {
            const int c = call * 256 + tid;
            const int row = c >> 3;
            const int slot = (c & 7) ^ (row & 7);
            int rg = bn + row; rg = rg < Nb ? rg : Nb - 1;
            const unsigned short* g = B + (size_t)rg * K + kt + slot * 8;
            __builtin_amdgcn_global_load_lds(
                (const __attribute__((address_space(1))) unsigned int*)g,
                (__attribute__((address_space(3))) unsigned int*)&Bs[c * 8], 16, 0, 0);
        }
        __syncthreads();
        // ---- compute: 4 K-substeps of 16
        #pragma unroll
        for (int ks = 0; ks < 4; ++ks) {
            const int q = ks * 2 + (lane >> 5);      // 16B chunk within row
            half8 a[FM], b[FN];
            #pragma unroll
            for (int m = 0; m < FM; ++m) {
                const int row = wr * (BM / WM) + m * 32 + (lane & 31);
                const int s = q ^ (row & 7);         // swizzled read
                a[m] = *(const half8*)&As[row * 64 + s * 8];
            }
            #pragma unroll
            for (int n = 0; n < FN; ++n) {
                const int row = wc * (BN / WN) + n * 32 + (lane & 31);
                const int s = q ^ (row & 7);
                b[n] = *(const half8*)&Bs[row * 64 + s * 8];
            }
            #pragma unroll
            for (int m = 0; m < FM; ++m)
                #pragma unroll
                for (int n = 0; n < FN; ++n)
                    acc[m][n] = __builtin_amdgcn_mfma_f32_32x32x16_f16(
                        a[m], b[n], acc[m][n], 0, 0, 0);
        }
        __syncthreads();
    }
    // ---- epilogue: C/D layout col=lane&31, row=(reg&3)+8*(reg>>2)+4*(lane>>5)
    const int hl = lane >> 5;
    #pragma unroll
    for (int m = 0; m < FM; ++m) {
        #pragma unroll
        for (int n = 0; n < FN; ++n) {
            const int col = bn + wc * (BN / WN) + n * 32 + (lane & 31);
            if (col < Nb) {
                #pragma unroll
                for (int r = 0; r < 16; ++r) {
                    const int rl = (r & 3) + 8 * (r >> 2) + 4 * hl;
                    const size_t row = bm + wr * (BM / WM) + m * 32 + rl;
                    float v = acc[m][n][r];
                    if (EPI == 1) {
                        v += bias[col];
                        v = v > 0.f ? v : 0.1f * v;
                        Oh[row * (size_t)ldC + col] = f2h(v);
                    } else {
                        C[row * (size_t)ldC + col] = v;
                    }
                }
            }
        }
    }
}

// ---------------------------------------------------------------------------
// Fallback fp32 GEMM (proven path, used only if ws_size too small)
// ---------------------------------------------------------------------------
template <int ACT>
__global__ __launch_bounds__(256) void gemm_abt(
    const float* __restrict__ A, const float* __restrict__ B,
    float* __restrict__ C, const float* __restrict__ bias,
    int K, int ldC)
{
    __shared__ float As[16][132];
    __shared__ float Bs[16][68];
    const int bm = blockIdx.x * 128;
    const int bn = blockIdx.y * 64;
    const int tid = threadIdx.x;
    const int ty = tid >> 4;
    const int tx = tid & 15;
    float acc[8][4] = {};
    const float* Ab = A + (size_t)bm * K;
    const float* Bb = B + (size_t)bn * K;
    for (int kt = 0; kt < K; kt += 16) {
        #pragma unroll
        for (int j = 0; j < 2; ++j) {
            const int i = tid * 2 + j;
            const int row = i >> 2, kq = i & 3;
            const float4 v = *(const float4*)(Ab + (size_t)row * K + kt + kq * 4);
            As[kq*4+0][row] = v.x; As[kq*4+1][row] = v.y;
            As[kq*4+2][row] = v.z; As[kq*4+3][row] = v.w;
        }
        {
            const int row = tid >> 2, kq = tid & 3;
            const float4 v = *(const float4*)(Bb + (size_t)row * K + kt + kq * 4);
            Bs[kq*4+0][row] = v.x; Bs[kq*4+1][row] = v.y;
            Bs[kq*4+2][row] = v.z; Bs[kq*4+3][row] = v.w;
        }
        __syncthreads();
        #pragma unroll
        for (int kk = 0; kk < 16; ++kk) {
            float a[8], b[4];
            #pragma unroll
            for (int i2 = 0; i2 < 8; ++i2) a[i2] = As[kk][ty*8 + i2];
            #pragma unroll
            for (int j2 = 0; j2 < 4; ++j2) b[j2] = Bs[kk][tx*4 + j2];
            #pragma unroll
            for (int i2 = 0; i2 < 8; ++i2)
                #pragma unroll
                for (int j2 = 0; j2 < 4; ++j2)
                    acc[i2][j2] = fmaf(a[i2], b[j2], acc[i2][j2]);
        }
        __syncthreads();
    }
    #pragma unroll
    for (int i2 = 0; i2 < 8; ++i2) {
        const size_t r = bm + ty*8 + i2;
        #pragma unroll
        for (int j2 = 0; j2 < 4; ++j2) {
            const int cidx = bn + tx*4 + j2;
            float v = acc[i2][j2];
            if (ACT == 1) { v += bias[cidx]; v = v > 0.f ? v : 0.1f * v; }
            C[r * (size_t)ldC + cidx] = v;
        }
    }
}

// ---------------------------------------------------------------------------
extern "C" void kernel_launch(void* const* d_in, const int* in_sizes, int n_in,
                              void* d_out, int out_size, void* d_ws, size_t ws_size,
                              hipStream_t stream)
{
    const float* adj = (const float*)d_in[0];
    const float* x   = (const float*)d_in[1];
    const float* W1  = (const float*)d_in[2];  // [512,1024]
    const float* W2  = (const float*)d_in[3];  // [256,512]
    const float* Wm1 = (const float*)d_in[4];  // [64,256]
    const float* Wm2 = (const float*)d_in[5];
    const float* Wm3 = (const float*)d_in[6];
    const float* Wt  = (const float*)d_in[7];  // [192,192]
    const float* bt  = (const float*)d_in[8];  // [192]
    float* out = (float*)d_out;

    // output layout (flat, return order): pred, sigmoid(x1), sigmoid(x2), z
    float* pred = out;                       // 8192*8192
    float* sig1 = out + 67108864;            // 8192*512
    float* sig2 = sig1 + 4194304;            // 8192*256
    float* z    = sig2 + 2097152;            // 8192*192

    // ---- workspace layout (fp16 path): ~51 MB
    char* w = (char*)d_ws;
    float* F  = (float*)w;                     w += (size_t)8192*512*4;      // 16 MB fp32 scratch
    unsigned short* Xh = (unsigned short*)w;   w += (size_t)8192*1024*2;     // 16 MB fp16 activations
    unsigned short* Wh = (unsigned short*)w;   w += (size_t)512*1024*2;      // 1 MB fp16 weights
    unsigned short* Zh = (unsigned short*)w;   w += (size_t)8192*192*2;      // 3 MB fp16 z
    unsigned short* Th = (unsigned short*)w;   w += (size_t)8192*192*2;      // 3 MB fp16 trans_z
    float* vals = (float*)w;                   w += (size_t)NN*CAP*4;        // 8 MB
    unsigned short* cols = (unsigned short*)w; w += (size_t)NN*CAP*2;        // 4 MB
    int* cnt = (int*)w;                        w += (size_t)NN*4;
    const size_t need = (size_t)(w - (char*)d_ws);

    if (ws_size < need) {
        // -------- fallback: proven fp32 path (needs ~46 MB) --------
        float* bufA = (float*)d_ws;
        float* bufB = bufA + 4194304;
        float* fvals = bufB + 4194304;
        unsigned short* fcols = (unsigned short*)(fvals + (size_t)NN * CAP);
        int* fcnt = (int*)(fcols + (size_t)NN * CAP);
        build_csr<<<NN, 256, 0, stream>>>(adj, fcols, fvals, fcnt);
        gemm_abt<0><<<dim3(64, 8), 256, 0, stream>>>(x, W1, bufA, nullptr, 1024, 512);
        spmm_kernel<512, 1, 1, 1, 0><<<NN, 512, 0, stream>>>(fcols, fvals, fcnt, bufA, bufB, sig1, nullptr);
        gemm_abt<0><<<dim3(64, 4), 256, 0, stream>>>(bufB, W2, bufA, nullptr, 512, 256);
        spmm_kernel<256, 1, 1, 1, 0><<<NN, 256, 0, stream>>>(fcols, fvals, fcnt, bufA, bufB, sig2, nullptr);
        gemm_abt<0><<<dim3(64, 1), 256, 0, stream>>>(bufB, Wm1, bufA +   0, nullptr, 256, 192);
        gemm_abt<0><<<dim3(64, 1), 256, 0, stream>>>(bufB, Wm2, bufA +  64, nullptr, 256, 192);
        gemm_abt<0><<<dim3(64, 1), 256, 0, stream>>>(bufB, Wm3, bufA + 128, nullptr, 256, 192);
        spmm_kernel<192, 0, 0, 1, 0><<<NN, 192, 0, stream>>>(fcols, fvals, fcnt, bufA, z, nullptr, nullptr);
        gemm_abt<1><<<dim3(64, 3), 256, 0, stream>>>(z, Wt, bufB, bt, 192, 192);
        gemm_abt<0><<<dim3(64, 128), 256, 0, stream>>>(z, bufB, pred, nullptr, 192, 8192);
        return;
    }

    // -------- fp16 single-pass MFMA path --------
    build_csr<<<NN, 256, 0, stream>>>(adj, cols, vals, cnt);

    // layer 1: x1 = relu(adj @ (x @ W1^T)); sig1 = sigmoid(x1); x1 -> Xh (fp16)
    pack_f16<<<2048, 256, 0, stream>>>(x,  Xh, 8192*1024/4);
    pack_f16<<<512,  256, 0, stream>>>(W1, Wh, 512*1024/4);
    gemm_f16<64, 128, 2, 2, 0><<<dim3(128, 4), 256, 0, stream>>>(
        Xh, Wh, F, nullptr, nullptr, 1024, 512, 512);
    spmm_kernel<512, 1, 1, 0, 1><<<NN, 512, 0, stream>>>(
        cols, vals, cnt, F, nullptr, sig1, Xh);

    // layer 2: x2 = relu(adj @ (x1 @ W2^T)); sig2 = sigmoid(x2); x2 -> Xh (fp16)
    pack_f16<<<128, 256, 0, stream>>>(W2, Wh, 256*512/4);
    gemm_f16<64, 128, 2, 2, 0><<<dim3(128, 2), 256, 0, stream>>>(
        Xh, Wh, F, nullptr, nullptr, 512, 256, 256);
    spmm_kernel<256, 1, 1, 0, 1><<<NN, 256, 0, stream>>>(
        cols, vals, cnt, F, nullptr, sig2, Xh);

    // heads: z = adj @ (x2 @ [Wm1;Wm2;Wm3]^T); z fp32 out + Zh fp16
    pack_f16<<<16, 256, 0, stream>>>(Wm1, Wh,           64*256/4);
    pack_f16<<<16, 256, 0, stream>>>(Wm2, Wh +  64*256, 64*256/4);
    pack_f16<<<16, 256, 0, stream>>>(Wm3, Wh + 128*256, 64*256/4);
    gemm_f16<64, 64, 2, 2, 0><<<dim3(128, 3), 256, 0, stream>>>(
        Xh, Wh, F, nullptr, nullptr, 256, 192, 192);
    spmm_kernel<192, 0, 0, 1, 1><<<NN, 192, 0, stream>>>(
        cols, vals, cnt, F, z, nullptr, Zh);

    // trans_z = leaky_relu(z @ Wt^T + bt) -> Th (fp16, fused epilogue)
    pack_f16<<<36, 256, 0, stream>>>(Wt, Wh, 192*192/4);
    gemm_f16<64, 64, 2, 2, 1><<<dim3(128, 3), 256, 0, stream>>>(
        Zh, Wh, nullptr, Th, bt, 192, 192, 192);

    // pred = z @ trans_z^T  [8192 x 8192], 256x128 tile
    gemm_f16<256, 128, 2, 2, 0><<<dim3(32, 64), 256, 0, stream>>>(
        Zh, Th, pred, nullptr, nullptr, 192, 8192, 8192);
}